// Round 3
// baseline (371.490 us; speedup 1.0000x reference)
//
#include <hip/hip_runtime.h>
#include <hip/hip_bf16.h>
#include <hip/hip_cooperative_groups.h>

namespace cg = cooperative_groups;

typedef __attribute__((ext_vector_type(8))) short short8;
typedef __attribute__((ext_vector_type(4))) float floatx4;

static constexpr int Hh = 56, Wd = 56, HWsz = 3136;
static constexpr int FGRID = 512;          // persistent grid: 2 blocks/CU
static constexpr float EPS = 1e-5f;

__device__ __forceinline__ unsigned short f2bf(float f) {
    __hip_bfloat16 h = __float2bfloat16(f);
    return *reinterpret_cast<unsigned short*>(&h);
}
__device__ __forceinline__ unsigned pack2(float a, float b) {
    return (unsigned)f2bf(a) | ((unsigned)f2bf(b) << 16);
}
__device__ __forceinline__ short8 pack8(float4 a, float4 b) {
    union { unsigned u[4]; short8 s; } c;
    c.u[0] = pack2(a.x, a.y); c.u[1] = pack2(a.z, a.w);
    c.u[2] = pack2(b.x, b.y); c.u[3] = pack2(b.z, b.w);
    return c.s;
}

struct P {
    const float *x, *w1, *c1w;
    const float *bn1g, *bn1b, *bn1m, *bn1v;
    const float *ibg, *ibb, *ibm, *ibv;
    const float *c2w, *c2b;
    const float *bn2g, *bn2b, *bn2m, *bn2v;
    const float *w3;
    const float *bn3g, *bn3b, *bn3m, *bn3v;
    float *out1c;            // [b][ch>>3][hw][8] fp32
    float *tbufp;            // [b][hw][16] fp32
    unsigned short *out2b;   // [b][hw][64] bf16
    unsigned short *w3p;     // packed A-frags for conv3
    float *out;
};

// ---------------------------------------------------------------------------
// w3 -> w3p A-fragment pack (64 blocks x 256 thr covers 16384 entries)
// ---------------------------------------------------------------------------
__device__ __forceinline__ void packw3_body(const P& p, int gid) {
    const int j = gid & 7, ln = (gid >> 3) & 63, ks = (gid >> 9) & 1, mb = gid >> 10;
    const int m = mb * 16 + (ln & 15), k = ks * 32 + ((ln >> 4) & 3) * 8 + j;
    p.w3p[gid] = f2bf(p.w3[m * 64 + k]);
}

// ---------------------------------------------------------------------------
// Stage A: conv1 (MFMA, M=64 K=256 N=64px) + BN1 + ReLU -> out1c; fused
// branch (c1w MFMA + BN + ReLU) -> tbufp. One 64-px tile per `it`.
// ---------------------------------------------------------------------------
__device__ __forceinline__ void stageA_body(const P& p, int it, int tid,
    unsigned short* xls /*64*264*/, unsigned short* tls /*64*72*/)
{
    const int lane = tid & 63;
    const int n    = lane & 15;
    const int quad = lane >> 4;
    const int wv   = tid >> 6;
    const int pix0 = it * 64;
    const int b    = pix0 / HWsz;
    const int hw0  = pix0 - b * HWsz;

    // stage x: float4 loads along px, bf16 transpose into LDS
    {
        const int cp0 = tid & 15;
        const int px4 = (tid >> 4) & 15;
        const float* xb = p.x + (size_t)b * 256 * HWsz + hw0 + px4 * 4;
        unsigned short* dst = xls + (px4 * 4) * 264 + 2 * cp0;
#pragma unroll
        for (int i = 0; i < 8; ++i) {
            const float4 v0 = *reinterpret_cast<const float4*>(xb + (size_t)(32 * i + 2 * cp0) * HWsz);
            const float4 v1 = *reinterpret_cast<const float4*>(xb + (size_t)(32 * i + 2 * cp0 + 1) * HWsz);
            unsigned short* d = dst + 32 * i;
            *reinterpret_cast<unsigned*>(d)           = pack2(v0.x, v1.x);
            *reinterpret_cast<unsigned*>(d + 264)     = pack2(v0.y, v1.y);
            *reinterpret_cast<unsigned*>(d + 2 * 264) = pack2(v0.z, v1.z);
            *reinterpret_cast<unsigned*>(d + 3 * 264) = pack2(v0.w, v1.w);
        }
    }

    // A fragments packed in-register from fp32 w1 (L2-resident)
    short8 afr[8];
    {
        const float* wr = p.w1 + (wv * 16 + n) * 256 + quad * 8;
#pragma unroll
        for (int ks = 0; ks < 8; ++ks) {
            const float4 wa = *reinterpret_cast<const float4*>(wr + ks * 32);
            const float4 wb = *reinterpret_cast<const float4*>(wr + ks * 32 + 4);
            afr[ks] = pack8(wa, wb);
        }
    }
    __syncthreads();

    const floatx4 zero = {0.f, 0.f, 0.f, 0.f};
    floatx4 acc[4];
#pragma unroll
    for (int nt = 0; nt < 4; ++nt) acc[nt] = zero;

#pragma unroll
    for (int nt = 0; nt < 4; ++nt) {
        const unsigned short* bp = xls + (nt * 16 + n) * 264 + quad * 8;
#pragma unroll
        for (int ks = 0; ks < 8; ++ks) {
            const short8 bfr = *reinterpret_cast<const short8*>(bp + ks * 32);
            acc[nt] = __builtin_amdgcn_mfma_f32_16x16x32_bf16(afr[ks], bfr, acc[nt], 0, 0, 0);
        }
    }

    // epilogue: BN1 + ReLU -> out1c [b][c8][px][8] float4; tile -> tls bf16
    const int och = wv * 16 + quad * 4;
    float sr[4], og[4];
#pragma unroll
    for (int r = 0; r < 4; ++r) {
        sr[r] = p.bn1g[och + r] * rsqrtf(p.bn1v[och + r] + EPS);
        og[r] = p.bn1b[och + r] - p.bn1m[och + r] * sr[r];
    }
    float* obase = p.out1c + ((size_t)b * 8 + (och >> 3)) * (HWsz * 8) + (och & 7);
#pragma unroll
    for (int nt = 0; nt < 4; ++nt) {
        float f[4];
#pragma unroll
        for (int r = 0; r < 4; ++r)
            f[r] = fmaxf(fmaf(acc[nt][r], sr[r], og[r]), 0.f);
        const int px = nt * 16 + n;
        float4 fv; fv.x = f[0]; fv.y = f[1]; fv.z = f[2]; fv.w = f[3];
        *reinterpret_cast<float4*>(obase + (size_t)(hw0 + px) * 8) = fv;
        uint2 pk;
        pk.x = pack2(f[0], f[1]);
        pk.y = pack2(f[2], f[3]);
        *reinterpret_cast<uint2*>(tls + px * 72 + och) = pk;
    }
    __syncthreads();

    // branch: t = relu(bn(c1w @ tile)); wave wv owns px-subtile wv
    floatx4 tacc = zero;
    {
        const float* cr = p.c1w + n * 64 + quad * 8;
        const unsigned short* bp = tls + (wv * 16 + n) * 72 + quad * 8;
#pragma unroll
        for (int ks = 0; ks < 2; ++ks) {
            const float4 ca = *reinterpret_cast<const float4*>(cr + ks * 32);
            const float4 cb = *reinterpret_cast<const float4*>(cr + ks * 32 + 4);
            const short8 af = pack8(ca, cb);
            const short8 bf = *reinterpret_cast<const short8*>(bp + ks * 32);
            tacc = __builtin_amdgcn_mfma_f32_16x16x32_bf16(af, bf, tacc, 0, 0, 0);
        }
    }
    {
        const int g0 = quad * 4;
        float4 t4;
#pragma unroll
        for (int r = 0; r < 4; ++r) {
            const float s = p.ibg[g0 + r] * rsqrtf(p.ibv[g0 + r] + EPS);
            const float o = p.ibb[g0 + r] - p.ibm[g0 + r] * s;
            (&t4.x)[r] = fmaxf(fmaf(tacc[r], s, o), 0.f);
        }
        *reinterpret_cast<float4*>(p.tbufp + ((size_t)b * HWsz + hw0 + wv * 16 + n) * 16 + g0) = t4;
    }
    __syncthreads();   // protect xls/tls across persistent-loop iterations
}

// ---------------------------------------------------------------------------
// Stage B: involution + BN2 + ReLU. One tile = 4 rows x 56 cols x 16 ch
// (group g). it in [0, 896): bg = it/14 (b*4+g), rowt = it%14.
// 224 active compute threads; all 256 stage the 10x62 fp32 halo.
// ---------------------------------------------------------------------------
__device__ __forceinline__ void stageB_body(const P& p, int it, int tid,
    float* halo /*620*20 floats*/)
{
    const int rowt = it % 14;
    const int bg   = it / 14;
    const int b    = bg >> 2, g = bg & 3;
    const int ch0  = g * 16;
    const int r0   = rowt * 4;

    // halo staging: [rr*62+cc][16ch] fp32 (stride 20), from 2 planes of out1c
    const float* src0 = p.out1c + ((size_t)b * 8 + g * 2) * (HWsz * 8);
    const float* src1 = src0 + (size_t)HWsz * 8;
    for (int idx = tid; idx < 10 * 62; idx += 256) {
        const int rr = idx / 62, cc = idx - rr * 62;
        const int gr = r0 + rr - 3, gc = cc - 3;
        const bool in = (gr >= 0) & (gr < Hh) & (gc >= 0) & (gc < Wd);
        float4 a0 = {0.f,0.f,0.f,0.f}, a1 = a0, a2 = a0, a3 = a0;
        if (in) {
            const float* s0 = src0 + (size_t)(gr * Wd + gc) * 8;
            const float* s1 = src1 + (size_t)(gr * Wd + gc) * 8;
            a0 = *reinterpret_cast<const float4*>(s0);
            a1 = *reinterpret_cast<const float4*>(s0 + 4);
            a2 = *reinterpret_cast<const float4*>(s1);
            a3 = *reinterpret_cast<const float4*>(s1 + 4);
        }
        float* d = halo + idx * 20;
        *reinterpret_cast<float4*>(d)      = a0;
        *reinterpret_cast<float4*>(d + 4)  = a1;
        *reinterpret_cast<float4*>(d + 8)  = a2;
        *reinterpret_cast<float4*>(d + 12) = a3;
    }
    __syncthreads();

    if (tid < 224) {
        const int row = tid / 56;
        const int col = tid - row * 56;
        const int hw  = (r0 + row) * Wd + col;

        float tv[16];
        {
            const float* tp = p.tbufp + ((size_t)b * HWsz + hw) * 16;
#pragma unroll
            for (int q4 = 0; q4 < 4; ++q4)
                *reinterpret_cast<float4*>(tv + q4 * 4) = *reinterpret_cast<const float4*>(tp + q4 * 4);
        }
        float wk[49];
        {
            const float* cwb = p.c2w + g * 49 * 16;
            const float* cbb = p.c2b + g * 49;
#pragma unroll
            for (int j = 0; j < 49; ++j) {
                float a = cbb[j];
#pragma unroll
                for (int q = 0; q < 16; ++q)
                    a = fmaf(cwb[j * 16 + q], tv[q], a);
                wk[j] = a;
            }
        }

        float acc[16];
#pragma unroll
        for (int i = 0; i < 16; ++i) acc[i] = 0.f;

#pragma unroll
        for (int kh = 0; kh < 7; ++kh) {
#pragma unroll
            for (int kw = 0; kw < 7; ++kw) {
                const float* q = halo + ((row + kh) * 62 + (col + kw)) * 20;
                const float4 a0 = *reinterpret_cast<const float4*>(q);
                const float4 a1 = *reinterpret_cast<const float4*>(q + 4);
                const float4 a2 = *reinterpret_cast<const float4*>(q + 8);
                const float4 a3 = *reinterpret_cast<const float4*>(q + 12);
                const float w = wk[kh * 7 + kw];
                acc[0]  = fmaf(w, a0.x, acc[0]);
                acc[1]  = fmaf(w, a0.y, acc[1]);
                acc[2]  = fmaf(w, a0.z, acc[2]);
                acc[3]  = fmaf(w, a0.w, acc[3]);
                acc[4]  = fmaf(w, a1.x, acc[4]);
                acc[5]  = fmaf(w, a1.y, acc[5]);
                acc[6]  = fmaf(w, a1.z, acc[6]);
                acc[7]  = fmaf(w, a1.w, acc[7]);
                acc[8]  = fmaf(w, a2.x, acc[8]);
                acc[9]  = fmaf(w, a2.y, acc[9]);
                acc[10] = fmaf(w, a2.z, acc[10]);
                acc[11] = fmaf(w, a2.w, acc[11]);
                acc[12] = fmaf(w, a3.x, acc[12]);
                acc[13] = fmaf(w, a3.y, acc[13]);
                acc[14] = fmaf(w, a3.z, acc[14]);
                acc[15] = fmaf(w, a3.w, acc[15]);
            }
        }

        float f[16];
#pragma unroll
        for (int i = 0; i < 16; ++i) {
            const float s = p.bn2g[ch0 + i] * rsqrtf(p.bn2v[ch0 + i] + EPS);
            const float o = p.bn2b[ch0 + i] - p.bn2m[ch0 + i] * s;
            f[i] = fmaxf(fmaf(acc[i], s, o), 0.f);
        }
        uint4 p0, p1;
        p0.x = pack2(f[0], f[1]);   p0.y = pack2(f[2], f[3]);
        p0.z = pack2(f[4], f[5]);   p0.w = pack2(f[6], f[7]);
        p1.x = pack2(f[8], f[9]);   p1.y = pack2(f[10], f[11]);
        p1.z = pack2(f[12], f[13]); p1.w = pack2(f[14], f[15]);
        unsigned short* ob = p.out2b + ((size_t)b * HWsz + hw) * 64 + ch0;
        *reinterpret_cast<uint4*>(ob)     = p0;
        *reinterpret_cast<uint4*>(ob + 8) = p1;
    }
    __syncthreads();   // protect halo across persistent-loop iterations
}

// ---------------------------------------------------------------------------
// Stage C: conv3 (MFMA, M=256 K=64 N=64px) + BN3 + residual + ReLU.
// Wave-local LDS transpose epilogue -> float4 residual/store.
// ---------------------------------------------------------------------------
__device__ __forceinline__ void stageC_body(const P& p, int it, int tid,
    unsigned short* bls /*64*72*/, float* bnl /*512*/, float* ldst /*4*2*16*20*/)
{
    const int lane = tid & 63;
    const int n    = lane & 15;
    const int quad = lane >> 4;
    const int wv   = tid >> 6;
    const int pix0 = it * 64;
    const int b    = pix0 / HWsz;
    const int hw0  = pix0 - b * HWsz;

    {
        const int px = tid & 63;
        const int ck = tid >> 6;
        const unsigned short* ob = p.out2b + ((size_t)b * HWsz + hw0 + px) * 64;
        const uint4 v0 = *reinterpret_cast<const uint4*>(ob + ck * 8);
        const uint4 v1 = *reinterpret_cast<const uint4*>(ob + (ck + 4) * 8);
        *reinterpret_cast<uint4*>(bls + px * 72 + ck * 8)       = v0;
        *reinterpret_cast<uint4*>(bls + px * 72 + (ck + 4) * 8) = v1;
        const float s = p.bn3g[tid] * rsqrtf(p.bn3v[tid] + EPS);
        bnl[tid * 2]     = s;
        bnl[tid * 2 + 1] = p.bn3b[tid] - p.bn3m[tid] * s;
    }
    __syncthreads();

    short8 bf[2];
#pragma unroll
    for (int ks = 0; ks < 2; ++ks)
        bf[ks] = *reinterpret_cast<const short8*>(bls + (wv * 16 + n) * 72 + ks * 32 + quad * 8);

    const floatx4 zero = {0.f, 0.f, 0.f, 0.f};
    floatx4 acc[16];
#pragma unroll
    for (int mb = 0; mb < 16; ++mb) acc[mb] = zero;

    const uint4* wp = reinterpret_cast<const uint4*>(p.w3p);
#pragma unroll
    for (int mb = 0; mb < 16; ++mb) {
        union { uint4 u; short8 s; } a0, a1;
        a0.u = wp[(mb * 2 + 0) * 64 + lane];
        a1.u = wp[(mb * 2 + 1) * 64 + lane];
        acc[mb] = __builtin_amdgcn_mfma_f32_16x16x32_bf16(a0.s, bf[0], acc[mb], 0, 0, 0);
        acc[mb] = __builtin_amdgcn_mfma_f32_16x16x32_bf16(a1.s, bf[1], acc[mb], 0, 0, 0);
    }

    const int colg0 = hw0 + wv * 16;
    float* lt0 = ldst + wv * (2 * 16 * 20);
#pragma unroll
    for (int mb = 0; mb < 16; ++mb) {
        float* lt = lt0 + (mb & 1) * (16 * 20);
#pragma unroll
        for (int r = 0; r < 4; ++r) {
            const int o = mb * 16 + quad * 4 + r;
            const float2 so = *reinterpret_cast<const float2*>(&bnl[o * 2]);
            lt[(quad * 4 + r) * 20 + n] = fmaf(acc[mb][r], so.x, so.y);
        }
        const float4 t4 = *reinterpret_cast<const float4*>(lt + n * 20 + quad * 4);
        const size_t gi = ((size_t)b * 256 + mb * 16 + n) * HWsz + colg0 + quad * 4;
        const float4 xr = *reinterpret_cast<const float4*>(p.x + gi);
        float4 ov;
        ov.x = fmaxf(t4.x + xr.x, 0.f);
        ov.y = fmaxf(t4.y + xr.y, 0.f);
        ov.z = fmaxf(t4.z + xr.z, 0.f);
        ov.w = fmaxf(t4.w + xr.w, 0.f);
        *reinterpret_cast<float4*>(p.out + gi) = ov;
    }
    __syncthreads();   // protect bls across persistent-loop iterations
}

// ---------------------------------------------------------------------------
// Fused persistent cooperative kernel: A -> grid.sync -> B -> grid.sync -> C.
// 512 blocks x 256 thr, LDS 49.6 KB (union) -> 2 blocks/CU co-resident.
// ---------------------------------------------------------------------------
__global__ __launch_bounds__(256, 2) void fused(P p)
{
    __shared__ __align__(16) unsigned char smem[49600];
    unsigned short* xls = reinterpret_cast<unsigned short*>(smem);           // 33792 B
    unsigned short* tls = reinterpret_cast<unsigned short*>(smem + 33792);   // 9216 B
    float* halo = reinterpret_cast<float*>(smem);                            // 49600 B
    unsigned short* bls = reinterpret_cast<unsigned short*>(smem);           // 9216 B
    float* bnl  = reinterpret_cast<float*>(smem + 9216);                     // 2048 B
    float* ldst = reinterpret_cast<float*>(smem + 11264);                    // 10240 B

    const int tid = threadIdx.x;
    const int blk = blockIdx.x;

    if (blk < 64) packw3_body(p, blk * 256 + tid);

    for (int it = blk; it < 784; it += FGRID)
        stageA_body(p, it, tid, xls, tls);

    cg::this_grid().sync();

    for (int it = blk; it < 896; it += FGRID)
        stageB_body(p, it, tid, halo);

    cg::this_grid().sync();

    for (int it = blk; it < 784; it += FGRID)
        stageC_body(p, it, tid, bls, bnl, ldst);
}

// ---------------------------------------------------------------------------
// Fallback (non-cooperative) wrappers — identical math, 3 launches.
// ---------------------------------------------------------------------------
__global__ __launch_bounds__(256) void k1_sa(P p)
{
    __shared__ unsigned short xls[64 * 264];
    __shared__ unsigned short tls[64 * 72];
    if (blockIdx.x < 64) packw3_body(p, blockIdx.x * 256 + threadIdx.x);
    stageA_body(p, blockIdx.x, threadIdx.x, xls, tls);
}

__global__ __launch_bounds__(256) void k2_sb(P p)
{
    __shared__ float halo[620 * 20];
    stageB_body(p, blockIdx.x, threadIdx.x, halo);
}

__global__ __launch_bounds__(256) void k3_sc(P p)
{
    __shared__ unsigned short bls[64 * 72];
    __shared__ float bnl[512];
    __shared__ float ldst[4 * 2 * 16 * 20];
    stageC_body(p, blockIdx.x, threadIdx.x, bls, bnl, ldst);
}

extern "C" void kernel_launch(void* const* d_in, const int* in_sizes, int n_in,
                              void* d_out, int out_size, void* d_ws, size_t ws_size,
                              hipStream_t stream)
{
    // ws layout (float units)
    float* wsf = (float*)d_ws;

    P p;
    p.x    = (const float*)d_in[0];
    p.w1   = (const float*)d_in[1];
    p.bn1g = (const float*)d_in[2];
    p.bn1b = (const float*)d_in[3];
    p.bn1m = (const float*)d_in[4];
    p.bn1v = (const float*)d_in[5];
    p.c1w  = (const float*)d_in[6];
    p.ibg  = (const float*)d_in[7];
    p.ibb  = (const float*)d_in[8];
    p.ibm  = (const float*)d_in[9];
    p.ibv  = (const float*)d_in[10];
    p.c2w  = (const float*)d_in[11];
    p.c2b  = (const float*)d_in[12];
    p.bn2g = (const float*)d_in[13];
    p.bn2b = (const float*)d_in[14];
    p.bn2m = (const float*)d_in[15];
    p.bn2v = (const float*)d_in[16];
    p.w3   = (const float*)d_in[17];
    p.bn3g = (const float*)d_in[18];
    p.bn3b = (const float*)d_in[19];
    p.bn3m = (const float*)d_in[20];
    p.bn3v = (const float*)d_in[21];
    p.out1c = wsf;                                   // 3211264 f
    p.out2b = (unsigned short*)(wsf + 3211264);      // 3211264 us
    p.tbufp = wsf + 4816896;                         // 802816 f
    p.w3p   = (unsigned short*)(wsf + 5619712);      // 16384 us
    p.out   = (float*)d_out;

    static int coop = -1;
    if (coop < 0) {
        int v = 0;
        if (hipDeviceGetAttribute(&v, hipDeviceAttributeCooperativeLaunch, 0) != hipSuccess) v = 0;
        coop = v;
    }

    bool launched = false;
    if (coop) {
        void* args[] = { (void*)&p };
        hipError_t e = hipLaunchCooperativeKernel((const void*)fused, dim3(FGRID), dim3(256),
                                                  args, 0, stream);
        if (e == hipSuccess) launched = true;
        else (void)hipGetLastError();   // clear error, fall back
    }

    if (!launched) {
        k1_sa<<<dim3(784), dim3(256), 0, stream>>>(p);
        k2_sb<<<dim3(896), dim3(256), 0, stream>>>(p);
        k3_sc<<<dim3(784), dim3(256), 0, stream>>>(p);
    }
}

// Round 4
// 185.171 us; speedup vs baseline: 2.0062x; 2.0062x over previous
//
#include <hip/hip_runtime.h>
#include <hip/hip_bf16.h>

typedef __attribute__((ext_vector_type(8))) short short8;
typedef __attribute__((ext_vector_type(4))) float floatx4;

static constexpr int Hh = 56, Wd = 56, HWsz = 3136;
static constexpr float EPS = 1e-5f;

__device__ __forceinline__ unsigned short f2bf(float f) {
    __hip_bfloat16 h = __float2bfloat16(f);
    return *reinterpret_cast<unsigned short*>(&h);
}
__device__ __forceinline__ unsigned pack2(float a, float b) {
    return (unsigned)f2bf(a) | ((unsigned)f2bf(b) << 16);
}
__device__ __forceinline__ short8 pack8(float4 a, float4 b) {
    union { unsigned u[4]; short8 s; } c;
    c.u[0] = pack2(a.x, a.y); c.u[1] = pack2(a.z, a.w);
    c.u[2] = pack2(b.x, b.y); c.u[3] = pack2(b.z, b.w);
    return c.s;
}
__device__ __forceinline__ float bflo(unsigned w) {
    union { unsigned u; float f; } c; c.u = w << 16; return c.f;
}
__device__ __forceinline__ float bfhi(unsigned w) {
    union { unsigned u; float f; } c; c.u = w & 0xffff0000u; return c.f;
}

// ---------------------------------------------------------------------------
// K1: conv1 via MFMA (M=64 ch, K=256, N=64 px/block) + BN1 + ReLU.
// Weights packed in-register from fp32 w1/c1w (L2-resident).
// out1cb layout: [b][ch>>3][hw][8] BF16 — the same bf16 rounding the branch
// already consumes via tls; halves k1 write + k2 read traffic.
// tbufp layout: [b][hw][16] fp32.
// ---------------------------------------------------------------------------
__global__ __launch_bounds__(256) void k1_conv1_branch(
    const float* __restrict__ x, const float* __restrict__ w1,
    const float* __restrict__ c1w,
    const float* __restrict__ bn1g, const float* __restrict__ bn1b,
    const float* __restrict__ bn1m, const float* __restrict__ bn1v,
    const float* __restrict__ ibg, const float* __restrict__ ibb,
    const float* __restrict__ ibm, const float* __restrict__ ibv,
    unsigned short* __restrict__ out1cb, float* __restrict__ tbufp)
{
    __shared__ unsigned short xls[64 * 264];   // 33 KB: [px][c] bf16, stride 264
    __shared__ unsigned short tls[64 * 72];    // 9 KB:  [px][ch] bf16, stride 72
    const int tid  = threadIdx.x;
    const int lane = tid & 63;
    const int n    = lane & 15;
    const int quad = lane >> 4;
    const int wv   = tid >> 6;
    const int pix0 = blockIdx.x * 64;
    const int b    = pix0 / HWsz;
    const int hw0  = pix0 - b * HWsz;

    // stage x: thread (cp0 = tid&15, px4 = (tid>>4)&15) loads channel-pairs
    // cp0+16i as float4 along px (rows 4*px4..4*px4+3).
    {
        const int cp0 = tid & 15;
        const int px4 = (tid >> 4) & 15;
        const float* xb = x + (size_t)b * 256 * HWsz + hw0 + px4 * 4;
        unsigned short* dst = xls + (px4 * 4) * 264 + 2 * cp0;
#pragma unroll
        for (int i = 0; i < 8; ++i) {
            const float4 v0 = *reinterpret_cast<const float4*>(xb + (size_t)(32 * i + 2 * cp0) * HWsz);
            const float4 v1 = *reinterpret_cast<const float4*>(xb + (size_t)(32 * i + 2 * cp0 + 1) * HWsz);
            unsigned short* d = dst + 32 * i;
            *reinterpret_cast<unsigned*>(d)           = pack2(v0.x, v1.x);
            *reinterpret_cast<unsigned*>(d + 264)     = pack2(v0.y, v1.y);
            *reinterpret_cast<unsigned*>(d + 2 * 264) = pack2(v0.z, v1.z);
            *reinterpret_cast<unsigned*>(d + 3 * 264) = pack2(v0.w, v1.w);
        }
    }

    // A fragments packed in-register: m = wv*16+n, k = ks*32 + quad*8 + j
    short8 afr[8];
    {
        const float* wr = w1 + (wv * 16 + n) * 256 + quad * 8;
#pragma unroll
        for (int ks = 0; ks < 8; ++ks) {
            const float4 wa = *reinterpret_cast<const float4*>(wr + ks * 32);
            const float4 wb = *reinterpret_cast<const float4*>(wr + ks * 32 + 4);
            afr[ks] = pack8(wa, wb);
        }
    }
    __syncthreads();

    const floatx4 zero = {0.f, 0.f, 0.f, 0.f};
    floatx4 acc[4];
#pragma unroll
    for (int nt = 0; nt < 4; ++nt) acc[nt] = zero;

#pragma unroll
    for (int nt = 0; nt < 4; ++nt) {
        const unsigned short* bp = xls + (nt * 16 + n) * 264 + quad * 8;
#pragma unroll
        for (int ks = 0; ks < 8; ++ks) {
            const short8 bfr = *reinterpret_cast<const short8*>(bp + ks * 32);
            acc[nt] = __builtin_amdgcn_mfma_f32_16x16x32_bf16(afr[ks], bfr, acc[nt], 0, 0, 0);
        }
    }

    // epilogue: BN1 + ReLU; one bf16 pack serves BOTH out1cb and tls
    const int och = wv * 16 + quad * 4;
    float sr[4], og[4];
#pragma unroll
    for (int r = 0; r < 4; ++r) {
        sr[r] = bn1g[och + r] * rsqrtf(bn1v[och + r] + EPS);
        og[r] = bn1b[och + r] - bn1m[och + r] * sr[r];
    }
    unsigned short* obase = out1cb + ((size_t)b * 8 + (och >> 3)) * (HWsz * 8) + (och & 7);
#pragma unroll
    for (int nt = 0; nt < 4; ++nt) {
        float f[4];
#pragma unroll
        for (int r = 0; r < 4; ++r)
            f[r] = fmaxf(fmaf(acc[nt][r], sr[r], og[r]), 0.f);
        const int px = nt * 16 + n;
        uint2 pk;
        pk.x = pack2(f[0], f[1]);
        pk.y = pack2(f[2], f[3]);
        *reinterpret_cast<uint2*>(obase + (size_t)(hw0 + px) * 8) = pk;
        *reinterpret_cast<uint2*>(tls + px * 72 + och) = pk;
    }
    __syncthreads();

    // branch: t = relu(bn(c1w @ out1_tile)); wave wv does px-subtile wv
    floatx4 tacc = zero;
    {
        const float* cr = c1w + n * 64 + quad * 8;
        const unsigned short* bp = tls + (wv * 16 + n) * 72 + quad * 8;
#pragma unroll
        for (int ks = 0; ks < 2; ++ks) {
            const float4 ca = *reinterpret_cast<const float4*>(cr + ks * 32);
            const float4 cb = *reinterpret_cast<const float4*>(cr + ks * 32 + 4);
            const short8 af = pack8(ca, cb);
            const short8 bf = *reinterpret_cast<const short8*>(bp + ks * 32);
            tacc = __builtin_amdgcn_mfma_f32_16x16x32_bf16(af, bf, tacc, 0, 0, 0);
        }
    }
    {
        const int g0 = quad * 4;
        float4 t4;
#pragma unroll
        for (int r = 0; r < 4; ++r) {
            const float s = ibg[g0 + r] * rsqrtf(ibv[g0 + r] + EPS);
            const float o = ibb[g0 + r] - ibm[g0 + r] * s;
            (&t4.x)[r] = fmaxf(fmaf(tacc[r], s, o), 0.f);
        }
        *reinterpret_cast<float4*>(tbufp + ((size_t)b * HWsz + hw0 + wv * 16 + n) * 16 + g0) = t4;
    }
}

// ---------------------------------------------------------------------------
// K2: involution + BN2 + ReLU, full 16-channel group per block.
// grid (7, 64 bg), 448 thr, 1 px/thr. Halo staged from bf16 out1cb
// (2x uint4 per px), converted to fp32 in LDS [868 px][20 floats] —
// the 49-tap inner loop is unchanged (fp32 b128 reads at data floor).
// Tail of blockIdx.x==0 blocks packs w3p for k3.
// ---------------------------------------------------------------------------
__global__ __launch_bounds__(448) void k2_involution(
    const unsigned short* __restrict__ out1cb, const float* __restrict__ tbufp,
    const float* __restrict__ c2w, const float* __restrict__ c2b,
    const float* __restrict__ bn2g, const float* __restrict__ bn2b,
    const float* __restrict__ bn2m, const float* __restrict__ bn2v,
    const float* __restrict__ w3, unsigned short* __restrict__ w3p,
    unsigned short* __restrict__ out2b)
{
    __shared__ float lds[14 * 62 * 20];   // 67.8 KB, pixel stride 20 floats
    const int r0  = blockIdx.x * 8;
    const int b   = blockIdx.y >> 2, g = blockIdx.y & 3;
    const int ch0 = g * 16;
    const int tid = threadIdx.x;
    const int row = tid / 56;
    const int col = tid - row * 56;
    const int hw  = (r0 + row) * Wd + col;

    // halo staging: [rr][cc][16ch] fp32 from bf16 out1cb (2 planes)
    const unsigned short* src0 = out1cb + ((size_t)b * 8 + g * 2) * (HWsz * 8);
    const unsigned short* src1 = src0 + (size_t)HWsz * 8;
    for (int idx = tid; idx < 14 * 62; idx += 448) {
        const int rr = idx / 62, cc = idx - rr * 62;
        const int gr = r0 + rr - 3, gc = cc - 3;
        const bool in = (gr >= 0) & (gr < Hh) & (gc >= 0) & (gc < Wd);
        uint4 q0 = {0u,0u,0u,0u}, q1 = {0u,0u,0u,0u};
        if (in) {
            q0 = *reinterpret_cast<const uint4*>(src0 + (size_t)(gr * Wd + gc) * 8);
            q1 = *reinterpret_cast<const uint4*>(src1 + (size_t)(gr * Wd + gc) * 8);
        }
        float4 a0, a1, a2, a3;
        a0.x = bflo(q0.x); a0.y = bfhi(q0.x); a0.z = bflo(q0.y); a0.w = bfhi(q0.y);
        a1.x = bflo(q0.z); a1.y = bfhi(q0.z); a1.z = bflo(q0.w); a1.w = bfhi(q0.w);
        a2.x = bflo(q1.x); a2.y = bfhi(q1.x); a2.z = bflo(q1.y); a2.w = bfhi(q1.y);
        a3.x = bflo(q1.z); a3.y = bfhi(q1.z); a3.z = bflo(q1.w); a3.w = bfhi(q1.w);
        float* d = &lds[idx * 20];
        *reinterpret_cast<float4*>(d)      = a0;
        *reinterpret_cast<float4*>(d + 4)  = a1;
        *reinterpret_cast<float4*>(d + 8)  = a2;
        *reinterpret_cast<float4*>(d + 12) = a3;
    }

    // per-pixel t (4x float4), then all 49 weights (pure VALU + s_load)
    float tv[16];
    {
        const float* tp = tbufp + ((size_t)b * HWsz + hw) * 16;
#pragma unroll
        for (int q4 = 0; q4 < 4; ++q4)
            *reinterpret_cast<float4*>(tv + q4 * 4) = *reinterpret_cast<const float4*>(tp + q4 * 4);
    }
    float wk[49];
    {
        const float* cwb = c2w + g * 49 * 16;
        const float* cbb = c2b + g * 49;
#pragma unroll
        for (int j = 0; j < 49; ++j) {
            float a = cbb[j];
#pragma unroll
            for (int q = 0; q < 16; ++q)
                a = fmaf(cwb[j * 16 + q], tv[q], a);
            wk[j] = a;
        }
    }
    __syncthreads();

    float acc[16];
#pragma unroll
    for (int i = 0; i < 16; ++i) acc[i] = 0.f;

#pragma unroll
    for (int kh = 0; kh < 7; ++kh) {
#pragma unroll
        for (int kw = 0; kw < 7; ++kw) {
            const float* p = &lds[((row + kh) * 62 + (col + kw)) * 20];
            const float4 a0 = *reinterpret_cast<const float4*>(p);
            const float4 a1 = *reinterpret_cast<const float4*>(p + 4);
            const float4 a2 = *reinterpret_cast<const float4*>(p + 8);
            const float4 a3 = *reinterpret_cast<const float4*>(p + 12);
            const float w = wk[kh * 7 + kw];
            acc[0]  = fmaf(w, a0.x, acc[0]);
            acc[1]  = fmaf(w, a0.y, acc[1]);
            acc[2]  = fmaf(w, a0.z, acc[2]);
            acc[3]  = fmaf(w, a0.w, acc[3]);
            acc[4]  = fmaf(w, a1.x, acc[4]);
            acc[5]  = fmaf(w, a1.y, acc[5]);
            acc[6]  = fmaf(w, a1.z, acc[6]);
            acc[7]  = fmaf(w, a1.w, acc[7]);
            acc[8]  = fmaf(w, a2.x, acc[8]);
            acc[9]  = fmaf(w, a2.y, acc[9]);
            acc[10] = fmaf(w, a2.z, acc[10]);
            acc[11] = fmaf(w, a2.w, acc[11]);
            acc[12] = fmaf(w, a3.x, acc[12]);
            acc[13] = fmaf(w, a3.y, acc[13]);
            acc[14] = fmaf(w, a3.z, acc[14]);
            acc[15] = fmaf(w, a3.w, acc[15]);
        }
    }

    float f[16];
#pragma unroll
    for (int i = 0; i < 16; ++i) {
        const float s = bn2g[ch0 + i] * rsqrtf(bn2v[ch0 + i] + EPS);
        const float o = bn2b[ch0 + i] - bn2m[ch0 + i] * s;
        f[i] = fmaxf(fmaf(acc[i], s, o), 0.f);
    }
    uint4 p0, p1;
    p0.x = pack2(f[0], f[1]);   p0.y = pack2(f[2], f[3]);
    p0.z = pack2(f[4], f[5]);   p0.w = pack2(f[6], f[7]);
    p1.x = pack2(f[8], f[9]);   p1.y = pack2(f[10], f[11]);
    p1.z = pack2(f[12], f[13]); p1.w = pack2(f[14], f[15]);
    unsigned short* ob = out2b + ((size_t)b * HWsz + hw) * 64 + ch0;
    *reinterpret_cast<uint4*>(ob)     = p0;
    *reinterpret_cast<uint4*>(ob + 8) = p1;

    // tail: pack w3 -> w3p (A-fragment order) for k3
    if (blockIdx.x == 0) {
        const int gid = blockIdx.y * 448 + tid;
        if (gid < 16384) {
            const int j = gid & 7, ln = (gid >> 3) & 63, ks = (gid >> 9) & 1, mb = gid >> 10;
            const int m = mb * 16 + (ln & 15), k = ks * 32 + ((ln >> 4) & 3) * 8 + j;
            w3p[gid] = f2bf(w3[m * 64 + k]);
        }
    }
}

// ---------------------------------------------------------------------------
// K3: conv3 via MFMA (M=256, K=64, N=64 px/block) + BN3 + residual + ReLU.
// BN3 folded inline. Wave-local LDS transpose epilogue -> float4 residual
// loads and stores.
// ---------------------------------------------------------------------------
__global__ __launch_bounds__(256) void k3_conv3(
    const unsigned short* __restrict__ out2b, const float* __restrict__ x,
    const unsigned short* __restrict__ w3p,
    const float* __restrict__ bn3g, const float* __restrict__ bn3b,
    const float* __restrict__ bn3m, const float* __restrict__ bn3v,
    float* __restrict__ out)
{
    __shared__ unsigned short bls[64 * 72];   // 9 KB bf16 [px][ch]
    __shared__ float bnl[512];                // (s,o) pairs for 256 outs
    __shared__ float ldst[4 * 2 * 16 * 20];   // 10 KB per-wave dbuf transpose
    const int tid  = threadIdx.x;
    const int lane = tid & 63;
    const int n    = lane & 15;
    const int quad = lane >> 4;
    const int wv   = tid >> 6;
    const int pix0 = blockIdx.x * 64;
    const int b    = pix0 / HWsz;
    const int hw0  = pix0 - b * HWsz;

    // stage out2b tile + BN3 fold
    {
        const int px = tid & 63;
        const int ck = tid >> 6;
        const unsigned short* ob = out2b + ((size_t)b * HWsz + hw0 + px) * 64;
        const uint4 v0 = *reinterpret_cast<const uint4*>(ob + ck * 8);
        const uint4 v1 = *reinterpret_cast<const uint4*>(ob + (ck + 4) * 8);
        *reinterpret_cast<uint4*>(bls + px * 72 + ck * 8)       = v0;
        *reinterpret_cast<uint4*>(bls + px * 72 + (ck + 4) * 8) = v1;
        const float s = bn3g[tid] * rsqrtf(bn3v[tid] + EPS);
        bnl[tid * 2]     = s;
        bnl[tid * 2 + 1] = bn3b[tid] - bn3m[tid] * s;
    }
    __syncthreads();

    short8 bf[2];
#pragma unroll
    for (int ks = 0; ks < 2; ++ks)
        bf[ks] = *reinterpret_cast<const short8*>(bls + (wv * 16 + n) * 72 + ks * 32 + quad * 8);

    const floatx4 zero = {0.f, 0.f, 0.f, 0.f};
    floatx4 acc[16];
#pragma unroll
    for (int mb = 0; mb < 16; ++mb) acc[mb] = zero;

    const uint4* wp = reinterpret_cast<const uint4*>(w3p);
#pragma unroll
    for (int mb = 0; mb < 16; ++mb) {
        union { uint4 u; short8 s; } a0, a1;
        a0.u = wp[(mb * 2 + 0) * 64 + lane];
        a1.u = wp[(mb * 2 + 1) * 64 + lane];
        acc[mb] = __builtin_amdgcn_mfma_f32_16x16x32_bf16(a0.s, bf[0], acc[mb], 0, 0, 0);
        acc[mb] = __builtin_amdgcn_mfma_f32_16x16x32_bf16(a1.s, bf[1], acc[mb], 0, 0, 0);
    }

    // epilogue: BN3 -> wave-local LDS transpose -> residual + ReLU (float4)
    const int colg0 = hw0 + wv * 16;
    float* lt0 = ldst + wv * (2 * 16 * 20);
#pragma unroll
    for (int mb = 0; mb < 16; ++mb) {
        float* lt = lt0 + (mb & 1) * (16 * 20);
#pragma unroll
        for (int r = 0; r < 4; ++r) {
            const int o = mb * 16 + quad * 4 + r;
            const float2 so = *reinterpret_cast<const float2*>(&bnl[o * 2]);
            lt[(quad * 4 + r) * 20 + n] = fmaf(acc[mb][r], so.x, so.y);
        }
        const float4 t4 = *reinterpret_cast<const float4*>(lt + n * 20 + quad * 4);
        const size_t gi = ((size_t)b * 256 + mb * 16 + n) * HWsz + colg0 + quad * 4;
        const float4 xr = *reinterpret_cast<const float4*>(x + gi);
        float4 ov;
        ov.x = fmaxf(t4.x + xr.x, 0.f);
        ov.y = fmaxf(t4.y + xr.y, 0.f);
        ov.z = fmaxf(t4.z + xr.z, 0.f);
        ov.w = fmaxf(t4.w + xr.w, 0.f);
        *reinterpret_cast<float4*>(out + gi) = ov;
    }
}

extern "C" void kernel_launch(void* const* d_in, const int* in_sizes, int n_in,
                              void* d_out, int out_size, void* d_ws, size_t ws_size,
                              hipStream_t stream)
{
    const float* x    = (const float*)d_in[0];
    const float* w1   = (const float*)d_in[1];
    const float* bn1g = (const float*)d_in[2];
    const float* bn1b = (const float*)d_in[3];
    const float* bn1m = (const float*)d_in[4];
    const float* bn1v = (const float*)d_in[5];
    const float* c1w  = (const float*)d_in[6];
    const float* ibg  = (const float*)d_in[7];
    const float* ibb  = (const float*)d_in[8];
    const float* ibm  = (const float*)d_in[9];
    const float* ibv  = (const float*)d_in[10];
    const float* c2w  = (const float*)d_in[11];
    const float* c2b  = (const float*)d_in[12];
    const float* bn2g = (const float*)d_in[13];
    const float* bn2b = (const float*)d_in[14];
    const float* bn2m = (const float*)d_in[15];
    const float* bn2v = (const float*)d_in[16];
    const float* w3   = (const float*)d_in[17];
    const float* bn3g = (const float*)d_in[18];
    const float* bn3b = (const float*)d_in[19];
    const float* bn3m = (const float*)d_in[20];
    const float* bn3v = (const float*)d_in[21];

    // ws layout (float units)
    float* wsf = (float*)d_ws;
    unsigned short* out1cb = (unsigned short*)wsf;                // 3211264 us -> 1605632 f
    unsigned short* out2b  = (unsigned short*)(wsf + 1605632);    // 3211264 us -> 1605632 f
    float*          tbufp  = wsf + 3211264;                       // 802816 f
    unsigned short* w3p    = (unsigned short*)(wsf + 4014080);    // 16384 us

    k1_conv1_branch<<<dim3(784), dim3(256), 0, stream>>>(
        x, w1, c1w, bn1g, bn1b, bn1m, bn1v, ibg, ibb, ibm, ibv, out1cb, tbufp);

    k2_involution<<<dim3(7, 64), dim3(448), 0, stream>>>(
        out1cb, tbufp, c2w, c2b, bn2g, bn2b, bn2m, bn2v, w3, w3p, out2b);

    k3_conv3<<<dim3(784), dim3(256), 0, stream>>>(
        out2b, x, w3p, bn3g, bn3b, bn3m, bn3v, (float*)d_out);
}